// Round 7
// baseline (443.242 us; speedup 1.0000x reference)
//
#include <hip/hip_runtime.h>
#include <math.h>

// QuantumNeuralNetwork: 12-qubit, 16-layer RY+CNOT-ring state-vector sim.
// Round 16: r14 gate structure (256 thr/state, 16 amps/lane, tan shears,
// per-wave trig table, all-DPP lane gates, global C-deferral) with the LDS
// trip buffer HALVED to 16 KB via slot-bit-11 phase splitting:
//   W1 bit11 = t7 (wave-uniform)    R1 bit11 = i3 (reg-uniform)
//   W2 bit11 = i3                   R2 bit11 = t7 ^ i0 (wave-uniform parity)
// Each trip: Wa bar Ra bar Wb bar Rb in a 2048-v2f buffer (slot & 0x7FF).
// 7 barriers/layer (vs 3), but 16 KB/block -> 8 blocks/CU = 32 waves/CU
// (full occupancy; r15's lesson: states/CU is LDS-pinned at 5..8, perf
// scales with waves per resident state).
// Clobber plugs (reg p_i overwritten by early reads before late writes):
//   trip1: hi waves (t7=1) save p0..p7 -> tv before R1a; W1b uses tv for 0..7.
//   trip2: parity waves save the 4 not-yet-written regs R2a clobbers.
// All cross-thread W/R collisions are barrier-separated; W2a and R1b share
// addresses only within the same thread (in-order DS pipe) - no bar needed.
// Arithmetic bit-identical to r14 -> absmax identical.
//
// Slot map F (GF(2)-linear, bijective; bank nibble = slot[3:0] untouched by
// the &0x7FF mask): s[3:0]=x[7:4]^Q(x[3:0]), s[7:4]=x[3:0], s[11:8]=x[11:8].
// Lane map: tn = t ^ 3*t2; L1 amp=(tn<<4)|i; L2 amp=(i<<8)|t;
// CNOT ring G folded into trip-2 read addressing (constants R2C).

#define DIM     4096
#define NLAYERS 16
#define BATCH   2048
#define NCLASS  5
#define HMSK    0x7FF

typedef float v2f __attribute__((ext_vector_type(2)));

__host__ __device__ constexpr unsigned gperm(unsigned i) {
  for (int q = 11; q >= 0; --q) {
    const unsigned cbit = 1u << (11 - q);
    const unsigned tbit = 1u << (11 - ((q + 1) % 12));
    if (i & cbit) i ^= tbit;
  }
  return i;
}
__host__ __device__ constexpr unsigned Qmap(unsigned lo) {
  return ((lo ^ (lo >> 3)) & 1u) | ((((lo >> 1) ^ (lo >> 3)) & 1u) << 1) |
         (((lo >> 2) & 1u) << 2) | ((lo & 1u) << 3);
}
__host__ __device__ constexpr unsigned Fmap(unsigned x) {
  return (x & 0xF00u) | ((x & 0xFu) << 4) | (((x >> 4) & 0xFu) ^ Qmap(x & 0xFu));
}

#define W1C(i) ((int)Fmap((unsigned)(i)))                    // < 256
#define R2C(i) ((int)(Fmap(gperm((unsigned)(i))) & HMSK))    // masked const

#define FOR16(M) M(0) M(1) M(2) M(3) M(4) M(5) M(6) M(7) M(8) M(9) M(10) \
  M(11) M(12) M(13) M(14) M(15)

// packed shear pair-rotation (kv, nkv in scope)
#define ROT(i, j) {                                          \
    const v2f ti = p##i, tj = p##j;                          \
    p##i = __builtin_elementwise_fma(nkv, tj, ti);           \
    p##j = __builtin_elementwise_fma(kv,  ti, tj); }

#define GM8 ROT(0,8) ROT(1,9) ROT(2,10) ROT(3,11) ROT(4,12) ROT(5,13) \
  ROT(6,14) ROT(7,15)
#define GM4 ROT(0,4) ROT(1,5) ROT(2,6) ROT(3,7) ROT(8,12) ROT(9,13) \
  ROT(10,14) ROT(11,15)
#define GM2 ROT(0,2) ROT(1,3) ROT(4,6) ROT(5,7) ROT(8,10) ROT(9,11) \
  ROT(12,14) ROT(13,15)
#define GM1 ROT(0,1) ROT(2,3) ROT(4,5) ROT(6,7) ROT(8,9) ROT(10,11) \
  ROT(12,13) ROT(14,15)

#define GETK(g) \
  const float kG = __int_as_float(__builtin_amdgcn_readlane( \
      __float_as_int(vkg[(g) & 3]), l + (((g) >> 2) << 4)));

// fused DPP shear on 8 v2f (16 comps): p += sg * dpp_xor(p); s_nop 1 covers
// the VALU-write -> DPP-read hazard; 16 distinct dsts -> no intra-block hazard
#define DPP8(CTRL, iA,iB,iC,iD,iE,iF,iG,iH) { \
    float a0 = p##iA.x, a1 = p##iA.y, a2 = p##iB.x, a3 = p##iB.y, \
          a4 = p##iC.x, a5 = p##iC.y, a6 = p##iD.x, a7 = p##iD.y, \
          a8 = p##iE.x, a9 = p##iE.y, a10 = p##iF.x, a11 = p##iF.y, \
          a12 = p##iG.x, a13 = p##iG.y, a14 = p##iH.x, a15 = p##iH.y; \
    asm("s_nop 1\n\t" \
        "v_fmac_f32_dpp %0, %0, %16 " CTRL "\n\t" \
        "v_fmac_f32_dpp %1, %1, %16 " CTRL "\n\t" \
        "v_fmac_f32_dpp %2, %2, %16 " CTRL "\n\t" \
        "v_fmac_f32_dpp %3, %3, %16 " CTRL "\n\t" \
        "v_fmac_f32_dpp %4, %4, %16 " CTRL "\n\t" \
        "v_fmac_f32_dpp %5, %5, %16 " CTRL "\n\t" \
        "v_fmac_f32_dpp %6, %6, %16 " CTRL "\n\t" \
        "v_fmac_f32_dpp %7, %7, %16 " CTRL "\n\t" \
        "v_fmac_f32_dpp %8, %8, %16 " CTRL "\n\t" \
        "v_fmac_f32_dpp %9, %9, %16 " CTRL "\n\t" \
        "v_fmac_f32_dpp %10, %10, %16 " CTRL "\n\t" \
        "v_fmac_f32_dpp %11, %11, %16 " CTRL "\n\t" \
        "v_fmac_f32_dpp %12, %12, %16 " CTRL "\n\t" \
        "v_fmac_f32_dpp %13, %13, %16 " CTRL "\n\t" \
        "v_fmac_f32_dpp %14, %14, %16 " CTRL "\n\t" \
        "v_fmac_f32_dpp %15, %15, %16 " CTRL \
        : "+v"(a0), "+v"(a1), "+v"(a2), "+v"(a3), "+v"(a4), "+v"(a5), \
          "+v"(a6), "+v"(a7), "+v"(a8), "+v"(a9), "+v"(a10), "+v"(a11), \
          "+v"(a12), "+v"(a13), "+v"(a14), "+v"(a15) \
        : "v"(sg)); \
    p##iA.x = a0;  p##iA.y = a1;  p##iB.x = a2;  p##iB.y = a3; \
    p##iC.x = a4;  p##iC.y = a5;  p##iD.x = a6;  p##iD.y = a7; \
    p##iE.x = a8;  p##iE.y = a9;  p##iF.x = a10; p##iF.y = a11; \
    p##iG.x = a12; p##iG.y = a13; p##iH.x = a14; p##iH.y = a15; }

#define DPPGATE(CTRL) \
  DPP8(CTRL, 0,1,2,3,4,5,6,7) DPP8(CTRL, 8,9,10,11,12,13,14,15)

__global__ __launch_bounds__(256, 8)
void qnn_sim(const float* __restrict__ zr, const float* __restrict__ zi,
             const float* __restrict__ thetas, const int* __restrict__ y,
             float* __restrict__ out) {
  __shared__ v2f buf2[2048];  // 16 KB half-state trip buffer
  const int b = blockIdx.x;
  const int t = threadIdx.x;  // 0..255

  const int tn = t ^ (((t >> 2) & 1) * 3);

  const int w1bm = ((((t & 0xF0) << 4) | (tn & 0xF)) & HMSK);   // F(tn<<4) masked
  const int r1b  = (int)Fmap((unsigned)t);                       // < 256
  const int Gtn  = ((tn << 4) ^ (tn << 3)) & 0xFFF;
  const int r2bm = (int)(Fmap((unsigned)Gtn) & HMSK);

  const bool wlo = (t < 128);  // t7==0: early W1 writer; R2a parity = even i

  // DPP gate sign masks
  const bool m7 = ((t ^ (t >> 2)) & 1) != 0;
  const bool m6 = (((t >> 1) ^ (t >> 2)) & 1) != 0;
  const bool m5 = ((t >> 2) & 1) != 0;
  const bool m4 = ((t >> 3) & 1) != 0;

  v2f p0,p1,p2,p3,p4,p5,p6,p7,p8,p9,p10,p11,p12,p13,p14,p15;
  v2f tv0,tv1,tv2,tv3,tv4,tv5,tv6,tv7;  // clobber-plug temps
  {
    const float4* zr4 = (const float4*)(zr + (size_t)b * DIM + (tn << 4));
    const float4* zi4 = (const float4*)(zi + (size_t)b * DIM + (tn << 4));
    const float4 a0 = zr4[0], a1 = zr4[1], a2 = zr4[2], a3 = zr4[3];
    const float4 b0 = zi4[0], b1 = zi4[1], b2 = zi4[2], b3 = zi4[3];
    p0  = (v2f){a0.x, b0.x}; p1  = (v2f){a0.y, b0.y};
    p2  = (v2f){a0.z, b0.z}; p3  = (v2f){a0.w, b0.w};
    p4  = (v2f){a1.x, b1.x}; p5  = (v2f){a1.y, b1.y};
    p6  = (v2f){a1.z, b1.z}; p7  = (v2f){a1.w, b1.w};
    p8  = (v2f){a2.x, b2.x}; p9  = (v2f){a2.y, b2.y};
    p10 = (v2f){a2.z, b2.z}; p11 = (v2f){a2.w, b2.w};
    p12 = (v2f){a3.x, b3.x}; p13 = (v2f){a3.y, b3.y};
    p14 = (v2f){a3.z, b3.z}; p15 = (v2f){a3.w, b3.w};
  }

  // per-wave trig table: lanes 0..47 k-values, 48..63 C_l
  float vkg[4];
  {
    const int lane = t & 63;
    if (lane < 48) {
      const int lsrc = lane & 15;
      const int gb = (lane >> 4) << 2;
#pragma unroll
      for (int j = 0; j < 4; ++j) {
        const float a = 0.5f * thetas[lsrc * 12 + gb + j];
        vkg[j] = sinf(a) / cosf(a);
      }
    } else {
      const int lsrc = lane - 48;
      float c = 1.f;
      for (int g = 0; g < 12; ++g) c *= cosf(0.5f * thetas[lsrc * 12 + g]);
      vkg[0] = c; vkg[1] = 0.f; vkg[2] = 0.f; vkg[3] = 0.f;
    }
  }
  float pcl = 1.f;
#pragma unroll
  for (int l2 = 0; l2 < NLAYERS; ++l2)
    pcl *= __int_as_float(__builtin_amdgcn_readlane(
        __float_as_int(vkg[0]), 48 + l2));
  const float pc2 = pcl * pcl;

#pragma unroll 1
  for (int l = 0; l < NLAYERS; ++l) {
    // ---- L1 gates: q8..q11 reg + q7,q6,q5,q4 DPP ----
    { GETK(8)  const v2f kv = {kG,kG}, nkv = {-kG,-kG}; GM8 }
    { GETK(9)  const v2f kv = {kG,kG}, nkv = {-kG,-kG}; GM4 }
    { GETK(10) const v2f kv = {kG,kG}, nkv = {-kG,-kG}; GM2 }
    { GETK(11) const v2f kv = {kG,kG}, nkv = {-kG,-kG}; GM1 }
    { GETK(7) const float sg = m7 ? kG : -kG;
      DPPGATE("quad_perm:[1,0,3,2] row_mask:0xf bank_mask:0xf") }
    { GETK(6) const float sg = m6 ? kG : -kG;
      DPPGATE("quad_perm:[2,3,0,1] row_mask:0xf bank_mask:0xf") }
    { GETK(5) const float sg = m5 ? kG : -kG;
      DPPGATE("row_half_mirror row_mask:0xf bank_mask:0xf") }
    { GETK(4) const float sg = m4 ? kG : -kG;
      DPPGATE("row_ror:8 row_mask:0xf bank_mask:0xf") }

    // ==== trip 1 (L1 -> L2), bit11-phased ====
    __syncthreads();                        // bar0: prev R2b done
    if (wlo) {                              // W1a: waves t7=0, all 16
#define W1P(i) buf2[w1bm ^ W1C(i)] = p##i;
      FOR16(W1P)
#undef W1P
    }
    __syncthreads();                        // bar1
    if (!wlo) { tv0=p0; tv1=p1; tv2=p2; tv3=p3;
                tv4=p4; tv5=p5; tv6=p6; tv7=p7; }  // save before clobber
    p0 = buf2[r1b];          p1 = buf2[r1b + 256];   // R1a: i<8
    p2 = buf2[r1b + 512];    p3 = buf2[r1b + 768];
    p4 = buf2[r1b + 1024];   p5 = buf2[r1b + 1280];
    p6 = buf2[r1b + 1536];   p7 = buf2[r1b + 1792];
    __syncthreads();                        // bar2: R1a done
    if (!wlo) {                             // W1b: waves t7=1
      buf2[w1bm ^ W1C(0)] = tv0; buf2[w1bm ^ W1C(1)] = tv1;
      buf2[w1bm ^ W1C(2)] = tv2; buf2[w1bm ^ W1C(3)] = tv3;
      buf2[w1bm ^ W1C(4)] = tv4; buf2[w1bm ^ W1C(5)] = tv5;
      buf2[w1bm ^ W1C(6)] = tv6; buf2[w1bm ^ W1C(7)] = tv7;
      buf2[w1bm ^ W1C(8)]  = p8;  buf2[w1bm ^ W1C(9)]  = p9;
      buf2[w1bm ^ W1C(10)] = p10; buf2[w1bm ^ W1C(11)] = p11;
      buf2[w1bm ^ W1C(12)] = p12; buf2[w1bm ^ W1C(13)] = p13;
      buf2[w1bm ^ W1C(14)] = p14; buf2[w1bm ^ W1C(15)] = p15;
    }
    __syncthreads();                        // bar3
    p8  = buf2[r1b];         p9  = buf2[r1b + 256];  // R1b: i>=8 (same masked)
    p10 = buf2[r1b + 512];   p11 = buf2[r1b + 768];
    p12 = buf2[r1b + 1024];  p13 = buf2[r1b + 1280];
    p14 = buf2[r1b + 1536];  p15 = buf2[r1b + 1792];

    // ---- L2 gates: q0..q3 ----
    { GETK(0) const v2f kv = {kG,kG}, nkv = {-kG,-kG}; GM8 }
    { GETK(1) const v2f kv = {kG,kG}, nkv = {-kG,-kG}; GM4 }
    { GETK(2) const v2f kv = {kG,kG}, nkv = {-kG,-kG}; GM2 }
    { GETK(3) const v2f kv = {kG,kG}, nkv = {-kG,-kG}; GM1 }

    // ==== trip 2 (L2 -> L1, G folded), bit11-phased ====
    // W2a: i<8, thread-own column addrs (same as own R1a/R1b -> no barrier)
    buf2[r1b]        = p0;  buf2[r1b + 256]  = p1;
    buf2[r1b + 512]  = p2;  buf2[r1b + 768]  = p3;
    buf2[r1b + 1024] = p4;  buf2[r1b + 1280] = p5;
    buf2[r1b + 1536] = p6;  buf2[r1b + 1792] = p7;
    if (wlo) { tv0 = p8;  tv1 = p10; tv2 = p12; tv3 = p14; }  // R2a clobbers evens
    else     { tv0 = p9;  tv1 = p11; tv2 = p13; tv3 = p15; }  // ... odds
    __syncthreads();                        // bar4
    if (wlo) {                              // R2a: even i (bit11 = 0^i0)
      p0  = buf2[r2bm ^ R2C(0)];  p2  = buf2[r2bm ^ R2C(2)];
      p4  = buf2[r2bm ^ R2C(4)];  p6  = buf2[r2bm ^ R2C(6)];
      p8  = buf2[r2bm ^ R2C(8)];  p10 = buf2[r2bm ^ R2C(10)];
      p12 = buf2[r2bm ^ R2C(12)]; p14 = buf2[r2bm ^ R2C(14)];
    } else {                                // R2a: odd i
      p1  = buf2[r2bm ^ R2C(1)];  p3  = buf2[r2bm ^ R2C(3)];
      p5  = buf2[r2bm ^ R2C(5)];  p7  = buf2[r2bm ^ R2C(7)];
      p9  = buf2[r2bm ^ R2C(9)];  p11 = buf2[r2bm ^ R2C(11)];
      p13 = buf2[r2bm ^ R2C(13)]; p15 = buf2[r2bm ^ R2C(15)];
    }
    __syncthreads();                        // bar5: R2a done
    if (wlo) {                              // W2b: i>=8; evens from temps
      buf2[r1b]        = tv0; buf2[r1b + 256]  = p9;
      buf2[r1b + 512]  = tv1; buf2[r1b + 768]  = p11;
      buf2[r1b + 1024] = tv2; buf2[r1b + 1280] = p13;
      buf2[r1b + 1536] = tv3; buf2[r1b + 1792] = p15;
    } else {                                // odds from temps
      buf2[r1b]        = p8;  buf2[r1b + 256]  = tv0;
      buf2[r1b + 512]  = p10; buf2[r1b + 768]  = tv1;
      buf2[r1b + 1024] = p12; buf2[r1b + 1280] = tv2;
      buf2[r1b + 1536] = p14; buf2[r1b + 1792] = tv3;
    }
    __syncthreads();                        // bar6
    if (wlo) {                              // R2b: odd i
      p1  = buf2[r2bm ^ R2C(1)];  p3  = buf2[r2bm ^ R2C(3)];
      p5  = buf2[r2bm ^ R2C(5)];  p7  = buf2[r2bm ^ R2C(7)];
      p9  = buf2[r2bm ^ R2C(9)];  p11 = buf2[r2bm ^ R2C(11)];
      p13 = buf2[r2bm ^ R2C(13)]; p15 = buf2[r2bm ^ R2C(15)];
    } else {                                // R2b: even i
      p0  = buf2[r2bm ^ R2C(0)];  p2  = buf2[r2bm ^ R2C(2)];
      p4  = buf2[r2bm ^ R2C(4)];  p6  = buf2[r2bm ^ R2C(6)];
      p8  = buf2[r2bm ^ R2C(8)];  p10 = buf2[r2bm ^ R2C(10)];
      p12 = buf2[r2bm ^ R2C(12)]; p14 = buf2[r2bm ^ R2C(14)];
    }
  }

  // ---- Z expectations ----
  float P = 0.f;
#define ACC(i) P = __builtin_fmaf(p##i.x, p##i.x, P); \
               P = __builtin_fmaf(p##i.y, p##i.y, P);
  FOR16(ACC)
#undef ACC
  P *= pc2;
  float e0 = ((t >> 7) & 1) ? -P : P;
  float e1 = ((t >> 6) & 1) ? -P : P;
  float e2 = ((t >> 5) & 1) ? -P : P;
  float e3 = ((t >> 4) & 1) ? -P : P;
  float e4 = ((t >> 3) & 1) ? -P : P;
#pragma unroll
  for (int off = 32; off >= 1; off >>= 1) {
    e0 += __shfl_xor(e0, off);
    e1 += __shfl_xor(e1, off);
    e2 += __shfl_xor(e2, off);
    e3 += __shfl_xor(e3, off);
    e4 += __shfl_xor(e4, off);
  }
  float* bf = (float*)buf2;
  __syncthreads();
  if ((t & 63) == 0) {
    const int w8 = (t >> 6) * 8;
    bf[w8 + 0] = e0; bf[w8 + 1] = e1; bf[w8 + 2] = e2;
    bf[w8 + 3] = e3; bf[w8 + 4] = e4;
  }
  __syncthreads();
  if (t == 0) {
    const float o0 = bf[0] + bf[8]  + bf[16] + bf[24];
    const float o1 = bf[1] + bf[9]  + bf[17] + bf[25];
    const float o2 = bf[2] + bf[10] + bf[18] + bf[26];
    const float o3 = bf[3] + bf[11] + bf[19] + bf[27];
    const float o4 = bf[4] + bf[12] + bf[20] + bf[28];
    float* op = out + 1 + (size_t)b * NCLASS;
    op[0] = o0; op[1] = o1; op[2] = o2; op[3] = o3; op[4] = o4;
    const float m = fmaxf(fmaxf(fmaxf(o0, o1), fmaxf(o2, o3)), o4);
    const float sum = expf(o0 - m) + expf(o1 - m) + expf(o2 - m) +
                      expf(o3 - m) + expf(o4 - m);
    const int yb = y[b];
    const float oy = (yb == 0) ? o0 : (yb == 1) ? o1 : (yb == 2) ? o2
                   : (yb == 3) ? o3 : o4;
    const float nll = (m + logf(sum)) - oy;
    atomicAdd(out, nll * (1.0f / BATCH));
  }
}

extern "C" void kernel_launch(void* const* d_in, const int* in_sizes, int n_in,
                              void* d_out, int out_size, void* d_ws, size_t ws_size,
                              hipStream_t stream) {
  const float* zr = (const float*)d_in[0];
  const float* zi = (const float*)d_in[1];
  const float* th = (const float*)d_in[2];
  const int*   y  = (const int*)d_in[3];
  float* out = (float*)d_out;
  hipMemsetAsync(out, 0, sizeof(float), stream);  // zero loss accumulator
  qnn_sim<<<BATCH, 256, 0, stream>>>(zr, zi, th, y, out);
}

// Round 8
// 199.169 us; speedup vs baseline: 2.2255x; 2.2255x over previous
//
#include <hip/hip_runtime.h>
#include <math.h>

// QuantumNeuralNetwork: 12-qubit, 16-layer RY+CNOT-ring state-vector sim.
// Round 17: round-16 structure UNCHANGED (256 thr/state, 16 amps/lane, tan
// shears, per-wave trig table, all-DPP lane gates, global C-deferral, 16 KB
// half-buffer trips via slot-bit-11 phasing, 7 barriers/layer) with the
// launch-bounds register clamp REMOVED. r16's __launch_bounds__(256,8) forced
// VGPR=32 -> all 16 p-regs + 8 temps spilled to scratch: FETCH 855 MB,
// WRITE 225 MB, HBM 3 TB/s, VALUBusy 21% - a spill-bound kernel. Steady-state
// dispatches still showed 90% occupancy, proving the 16 KB phasing achieves
// the intended residency. With the clamp gone the allocator takes ~60 VGPRs
// (no spill); occupancy lands wherever {VGPR, LDS=16KB} bind (>= 6 blk/CU).
//
// Phasing (verified r16, absmax bit-identical to r14):
//   W1 bit11 = t7 (wave-uniform)    R1 bit11 = i3 (reg-uniform)
//   W2 bit11 = i3                   R2 bit11 = t7 ^ i0 (wave-uniform parity)
// Each trip: Wa bar Ra bar Wb bar Rb in a 2048-v2f buffer (slot & 0x7FF).
// Clobber plugs: trip1 hi-waves save p0..7 pre-R1a; trip2 parity-save 4 regs.
// W2a/R1b share addresses only thread-locally (in-order DS pipe, no bar).
//
// Slot map F: s[3:0]=x[7:4]^Q(x[3:0]), s[7:4]=x[3:0], s[11:8]=x[11:8].
// Lane map: tn = t ^ 3*t2; L1 amp=(tn<<4)|i; L2 amp=(i<<8)|t;
// CNOT ring G folded into trip-2 read constants R2C.

#define DIM     4096
#define NLAYERS 16
#define BATCH   2048
#define NCLASS  5
#define HMSK    0x7FF

typedef float v2f __attribute__((ext_vector_type(2)));

__host__ __device__ constexpr unsigned gperm(unsigned i) {
  for (int q = 11; q >= 0; --q) {
    const unsigned cbit = 1u << (11 - q);
    const unsigned tbit = 1u << (11 - ((q + 1) % 12));
    if (i & cbit) i ^= tbit;
  }
  return i;
}
__host__ __device__ constexpr unsigned Qmap(unsigned lo) {
  return ((lo ^ (lo >> 3)) & 1u) | ((((lo >> 1) ^ (lo >> 3)) & 1u) << 1) |
         (((lo >> 2) & 1u) << 2) | ((lo & 1u) << 3);
}
__host__ __device__ constexpr unsigned Fmap(unsigned x) {
  return (x & 0xF00u) | ((x & 0xFu) << 4) | (((x >> 4) & 0xFu) ^ Qmap(x & 0xFu));
}

#define W1C(i) ((int)Fmap((unsigned)(i)))                    // < 256
#define R2C(i) ((int)(Fmap(gperm((unsigned)(i))) & HMSK))    // masked const

#define FOR16(M) M(0) M(1) M(2) M(3) M(4) M(5) M(6) M(7) M(8) M(9) M(10) \
  M(11) M(12) M(13) M(14) M(15)

// packed shear pair-rotation (kv, nkv in scope)
#define ROT(i, j) {                                          \
    const v2f ti = p##i, tj = p##j;                          \
    p##i = __builtin_elementwise_fma(nkv, tj, ti);           \
    p##j = __builtin_elementwise_fma(kv,  ti, tj); }

#define GM8 ROT(0,8) ROT(1,9) ROT(2,10) ROT(3,11) ROT(4,12) ROT(5,13) \
  ROT(6,14) ROT(7,15)
#define GM4 ROT(0,4) ROT(1,5) ROT(2,6) ROT(3,7) ROT(8,12) ROT(9,13) \
  ROT(10,14) ROT(11,15)
#define GM2 ROT(0,2) ROT(1,3) ROT(4,6) ROT(5,7) ROT(8,10) ROT(9,11) \
  ROT(12,14) ROT(13,15)
#define GM1 ROT(0,1) ROT(2,3) ROT(4,5) ROT(6,7) ROT(8,9) ROT(10,11) \
  ROT(12,13) ROT(14,15)

#define GETK(g) \
  const float kG = __int_as_float(__builtin_amdgcn_readlane( \
      __float_as_int(vkg[(g) & 3]), l + (((g) >> 2) << 4)));

// fused DPP shear on 8 v2f (16 comps): p += sg * dpp_xor(p); s_nop 1 covers
// the VALU-write -> DPP-read hazard; 16 distinct dsts -> no intra-block hazard
#define DPP8(CTRL, iA,iB,iC,iD,iE,iF,iG,iH) { \
    float a0 = p##iA.x, a1 = p##iA.y, a2 = p##iB.x, a3 = p##iB.y, \
          a4 = p##iC.x, a5 = p##iC.y, a6 = p##iD.x, a7 = p##iD.y, \
          a8 = p##iE.x, a9 = p##iE.y, a10 = p##iF.x, a11 = p##iF.y, \
          a12 = p##iG.x, a13 = p##iG.y, a14 = p##iH.x, a15 = p##iH.y; \
    asm("s_nop 1\n\t" \
        "v_fmac_f32_dpp %0, %0, %16 " CTRL "\n\t" \
        "v_fmac_f32_dpp %1, %1, %16 " CTRL "\n\t" \
        "v_fmac_f32_dpp %2, %2, %16 " CTRL "\n\t" \
        "v_fmac_f32_dpp %3, %3, %16 " CTRL "\n\t" \
        "v_fmac_f32_dpp %4, %4, %16 " CTRL "\n\t" \
        "v_fmac_f32_dpp %5, %5, %16 " CTRL "\n\t" \
        "v_fmac_f32_dpp %6, %6, %16 " CTRL "\n\t" \
        "v_fmac_f32_dpp %7, %7, %16 " CTRL "\n\t" \
        "v_fmac_f32_dpp %8, %8, %16 " CTRL "\n\t" \
        "v_fmac_f32_dpp %9, %9, %16 " CTRL "\n\t" \
        "v_fmac_f32_dpp %10, %10, %16 " CTRL "\n\t" \
        "v_fmac_f32_dpp %11, %11, %16 " CTRL "\n\t" \
        "v_fmac_f32_dpp %12, %12, %16 " CTRL "\n\t" \
        "v_fmac_f32_dpp %13, %13, %16 " CTRL "\n\t" \
        "v_fmac_f32_dpp %14, %14, %16 " CTRL "\n\t" \
        "v_fmac_f32_dpp %15, %15, %16 " CTRL \
        : "+v"(a0), "+v"(a1), "+v"(a2), "+v"(a3), "+v"(a4), "+v"(a5), \
          "+v"(a6), "+v"(a7), "+v"(a8), "+v"(a9), "+v"(a10), "+v"(a11), \
          "+v"(a12), "+v"(a13), "+v"(a14), "+v"(a15) \
        : "v"(sg)); \
    p##iA.x = a0;  p##iA.y = a1;  p##iB.x = a2;  p##iB.y = a3; \
    p##iC.x = a4;  p##iC.y = a5;  p##iD.x = a6;  p##iD.y = a7; \
    p##iE.x = a8;  p##iE.y = a9;  p##iF.x = a10; p##iF.y = a11; \
    p##iG.x = a12; p##iG.y = a13; p##iH.x = a14; p##iH.y = a15; }

#define DPPGATE(CTRL) \
  DPP8(CTRL, 0,1,2,3,4,5,6,7) DPP8(CTRL, 8,9,10,11,12,13,14,15)

__global__ __launch_bounds__(256)
void qnn_sim(const float* __restrict__ zr, const float* __restrict__ zi,
             const float* __restrict__ thetas, const int* __restrict__ y,
             float* __restrict__ out) {
  __shared__ v2f buf2[2048];  // 16 KB half-state trip buffer
  const int b = blockIdx.x;
  const int t = threadIdx.x;  // 0..255

  const int tn = t ^ (((t >> 2) & 1) * 3);

  const int w1bm = ((((t & 0xF0) << 4) | (tn & 0xF)) & HMSK);   // F(tn<<4) masked
  const int r1b  = (int)Fmap((unsigned)t);                       // < 256
  const int Gtn  = ((tn << 4) ^ (tn << 3)) & 0xFFF;
  const int r2bm = (int)(Fmap((unsigned)Gtn) & HMSK);

  const bool wlo = (t < 128);  // t7==0: early W1 writer; R2a parity = even i

  // DPP gate sign masks
  const bool m7 = ((t ^ (t >> 2)) & 1) != 0;
  const bool m6 = (((t >> 1) ^ (t >> 2)) & 1) != 0;
  const bool m5 = ((t >> 2) & 1) != 0;
  const bool m4 = ((t >> 3) & 1) != 0;

  v2f p0,p1,p2,p3,p4,p5,p6,p7,p8,p9,p10,p11,p12,p13,p14,p15;
  v2f tv0,tv1,tv2,tv3,tv4,tv5,tv6,tv7;  // clobber-plug temps
  {
    const float4* zr4 = (const float4*)(zr + (size_t)b * DIM + (tn << 4));
    const float4* zi4 = (const float4*)(zi + (size_t)b * DIM + (tn << 4));
    const float4 a0 = zr4[0], a1 = zr4[1], a2 = zr4[2], a3 = zr4[3];
    const float4 b0 = zi4[0], b1 = zi4[1], b2 = zi4[2], b3 = zi4[3];
    p0  = (v2f){a0.x, b0.x}; p1  = (v2f){a0.y, b0.y};
    p2  = (v2f){a0.z, b0.z}; p3  = (v2f){a0.w, b0.w};
    p4  = (v2f){a1.x, b1.x}; p5  = (v2f){a1.y, b1.y};
    p6  = (v2f){a1.z, b1.z}; p7  = (v2f){a1.w, b1.w};
    p8  = (v2f){a2.x, b2.x}; p9  = (v2f){a2.y, b2.y};
    p10 = (v2f){a2.z, b2.z}; p11 = (v2f){a2.w, b2.w};
    p12 = (v2f){a3.x, b3.x}; p13 = (v2f){a3.y, b3.y};
    p14 = (v2f){a3.z, b3.z}; p15 = (v2f){a3.w, b3.w};
  }

  // per-wave trig table: lanes 0..47 k-values, 48..63 C_l
  float vkg[4];
  {
    const int lane = t & 63;
    if (lane < 48) {
      const int lsrc = lane & 15;
      const int gb = (lane >> 4) << 2;
#pragma unroll
      for (int j = 0; j < 4; ++j) {
        const float a = 0.5f * thetas[lsrc * 12 + gb + j];
        vkg[j] = sinf(a) / cosf(a);
      }
    } else {
      const int lsrc = lane - 48;
      float c = 1.f;
      for (int g = 0; g < 12; ++g) c *= cosf(0.5f * thetas[lsrc * 12 + g]);
      vkg[0] = c; vkg[1] = 0.f; vkg[2] = 0.f; vkg[3] = 0.f;
    }
  }
  float pcl = 1.f;
#pragma unroll
  for (int l2 = 0; l2 < NLAYERS; ++l2)
    pcl *= __int_as_float(__builtin_amdgcn_readlane(
        __float_as_int(vkg[0]), 48 + l2));
  const float pc2 = pcl * pcl;

#pragma unroll 1
  for (int l = 0; l < NLAYERS; ++l) {
    // ---- L1 gates: q8..q11 reg + q7,q6,q5,q4 DPP ----
    { GETK(8)  const v2f kv = {kG,kG}, nkv = {-kG,-kG}; GM8 }
    { GETK(9)  const v2f kv = {kG,kG}, nkv = {-kG,-kG}; GM4 }
    { GETK(10) const v2f kv = {kG,kG}, nkv = {-kG,-kG}; GM2 }
    { GETK(11) const v2f kv = {kG,kG}, nkv = {-kG,-kG}; GM1 }
    { GETK(7) const float sg = m7 ? kG : -kG;
      DPPGATE("quad_perm:[1,0,3,2] row_mask:0xf bank_mask:0xf") }
    { GETK(6) const float sg = m6 ? kG : -kG;
      DPPGATE("quad_perm:[2,3,0,1] row_mask:0xf bank_mask:0xf") }
    { GETK(5) const float sg = m5 ? kG : -kG;
      DPPGATE("row_half_mirror row_mask:0xf bank_mask:0xf") }
    { GETK(4) const float sg = m4 ? kG : -kG;
      DPPGATE("row_ror:8 row_mask:0xf bank_mask:0xf") }

    // ==== trip 1 (L1 -> L2), bit11-phased ====
    __syncthreads();                        // bar0: prev R2b done
    if (wlo) {                              // W1a: waves t7=0, all 16
#define W1P(i) buf2[w1bm ^ W1C(i)] = p##i;
      FOR16(W1P)
#undef W1P
    }
    __syncthreads();                        // bar1
    if (!wlo) { tv0=p0; tv1=p1; tv2=p2; tv3=p3;
                tv4=p4; tv5=p5; tv6=p6; tv7=p7; }  // save before clobber
    p0 = buf2[r1b];          p1 = buf2[r1b + 256];   // R1a: i<8
    p2 = buf2[r1b + 512];    p3 = buf2[r1b + 768];
    p4 = buf2[r1b + 1024];   p5 = buf2[r1b + 1280];
    p6 = buf2[r1b + 1536];   p7 = buf2[r1b + 1792];
    __syncthreads();                        // bar2: R1a done
    if (!wlo) {                             // W1b: waves t7=1
      buf2[w1bm ^ W1C(0)] = tv0; buf2[w1bm ^ W1C(1)] = tv1;
      buf2[w1bm ^ W1C(2)] = tv2; buf2[w1bm ^ W1C(3)] = tv3;
      buf2[w1bm ^ W1C(4)] = tv4; buf2[w1bm ^ W1C(5)] = tv5;
      buf2[w1bm ^ W1C(6)] = tv6; buf2[w1bm ^ W1C(7)] = tv7;
      buf2[w1bm ^ W1C(8)]  = p8;  buf2[w1bm ^ W1C(9)]  = p9;
      buf2[w1bm ^ W1C(10)] = p10; buf2[w1bm ^ W1C(11)] = p11;
      buf2[w1bm ^ W1C(12)] = p12; buf2[w1bm ^ W1C(13)] = p13;
      buf2[w1bm ^ W1C(14)] = p14; buf2[w1bm ^ W1C(15)] = p15;
    }
    __syncthreads();                        // bar3
    p8  = buf2[r1b];         p9  = buf2[r1b + 256];  // R1b: i>=8 (same masked)
    p10 = buf2[r1b + 512];   p11 = buf2[r1b + 768];
    p12 = buf2[r1b + 1024];  p13 = buf2[r1b + 1280];
    p14 = buf2[r1b + 1536];  p15 = buf2[r1b + 1792];

    // ---- L2 gates: q0..q3 ----
    { GETK(0) const v2f kv = {kG,kG}, nkv = {-kG,-kG}; GM8 }
    { GETK(1) const v2f kv = {kG,kG}, nkv = {-kG,-kG}; GM4 }
    { GETK(2) const v2f kv = {kG,kG}, nkv = {-kG,-kG}; GM2 }
    { GETK(3) const v2f kv = {kG,kG}, nkv = {-kG,-kG}; GM1 }

    // ==== trip 2 (L2 -> L1, G folded), bit11-phased ====
    // W2a: i<8, thread-own column addrs (same as own R1a/R1b -> no barrier)
    buf2[r1b]        = p0;  buf2[r1b + 256]  = p1;
    buf2[r1b + 512]  = p2;  buf2[r1b + 768]  = p3;
    buf2[r1b + 1024] = p4;  buf2[r1b + 1280] = p5;
    buf2[r1b + 1536] = p6;  buf2[r1b + 1792] = p7;
    if (wlo) { tv0 = p8;  tv1 = p10; tv2 = p12; tv3 = p14; }  // R2a clobbers evens
    else     { tv0 = p9;  tv1 = p11; tv2 = p13; tv3 = p15; }  // ... odds
    __syncthreads();                        // bar4
    if (wlo) {                              // R2a: even i (bit11 = 0^i0)
      p0  = buf2[r2bm ^ R2C(0)];  p2  = buf2[r2bm ^ R2C(2)];
      p4  = buf2[r2bm ^ R2C(4)];  p6  = buf2[r2bm ^ R2C(6)];
      p8  = buf2[r2bm ^ R2C(8)];  p10 = buf2[r2bm ^ R2C(10)];
      p12 = buf2[r2bm ^ R2C(12)]; p14 = buf2[r2bm ^ R2C(14)];
    } else {                                // R2a: odd i
      p1  = buf2[r2bm ^ R2C(1)];  p3  = buf2[r2bm ^ R2C(3)];
      p5  = buf2[r2bm ^ R2C(5)];  p7  = buf2[r2bm ^ R2C(7)];
      p9  = buf2[r2bm ^ R2C(9)];  p11 = buf2[r2bm ^ R2C(11)];
      p13 = buf2[r2bm ^ R2C(13)]; p15 = buf2[r2bm ^ R2C(15)];
    }
    __syncthreads();                        // bar5: R2a done
    if (wlo) {                              // W2b: i>=8; evens from temps
      buf2[r1b]        = tv0; buf2[r1b + 256]  = p9;
      buf2[r1b + 512]  = tv1; buf2[r1b + 768]  = p11;
      buf2[r1b + 1024] = tv2; buf2[r1b + 1280] = p13;
      buf2[r1b + 1536] = tv3; buf2[r1b + 1792] = p15;
    } else {                                // odds from temps
      buf2[r1b]        = p8;  buf2[r1b + 256]  = tv0;
      buf2[r1b + 512]  = p10; buf2[r1b + 768]  = tv1;
      buf2[r1b + 1024] = p12; buf2[r1b + 1280] = tv2;
      buf2[r1b + 1536] = p14; buf2[r1b + 1792] = tv3;
    }
    __syncthreads();                        // bar6
    if (wlo) {                              // R2b: odd i
      p1  = buf2[r2bm ^ R2C(1)];  p3  = buf2[r2bm ^ R2C(3)];
      p5  = buf2[r2bm ^ R2C(5)];  p7  = buf2[r2bm ^ R2C(7)];
      p9  = buf2[r2bm ^ R2C(9)];  p11 = buf2[r2bm ^ R2C(11)];
      p13 = buf2[r2bm ^ R2C(13)]; p15 = buf2[r2bm ^ R2C(15)];
    } else {                                // R2b: even i
      p0  = buf2[r2bm ^ R2C(0)];  p2  = buf2[r2bm ^ R2C(2)];
      p4  = buf2[r2bm ^ R2C(4)];  p6  = buf2[r2bm ^ R2C(6)];
      p8  = buf2[r2bm ^ R2C(8)];  p10 = buf2[r2bm ^ R2C(10)];
      p12 = buf2[r2bm ^ R2C(12)]; p14 = buf2[r2bm ^ R2C(14)];
    }
  }

  // ---- Z expectations ----
  float P = 0.f;
#define ACC(i) P = __builtin_fmaf(p##i.x, p##i.x, P); \
               P = __builtin_fmaf(p##i.y, p##i.y, P);
  FOR16(ACC)
#undef ACC
  P *= pc2;
  float e0 = ((t >> 7) & 1) ? -P : P;
  float e1 = ((t >> 6) & 1) ? -P : P;
  float e2 = ((t >> 5) & 1) ? -P : P;
  float e3 = ((t >> 4) & 1) ? -P : P;
  float e4 = ((t >> 3) & 1) ? -P : P;
#pragma unroll
  for (int off = 32; off >= 1; off >>= 1) {
    e0 += __shfl_xor(e0, off);
    e1 += __shfl_xor(e1, off);
    e2 += __shfl_xor(e2, off);
    e3 += __shfl_xor(e3, off);
    e4 += __shfl_xor(e4, off);
  }
  float* bf = (float*)buf2;
  __syncthreads();
  if ((t & 63) == 0) {
    const int w8 = (t >> 6) * 8;
    bf[w8 + 0] = e0; bf[w8 + 1] = e1; bf[w8 + 2] = e2;
    bf[w8 + 3] = e3; bf[w8 + 4] = e4;
  }
  __syncthreads();
  if (t == 0) {
    const float o0 = bf[0] + bf[8]  + bf[16] + bf[24];
    const float o1 = bf[1] + bf[9]  + bf[17] + bf[25];
    const float o2 = bf[2] + bf[10] + bf[18] + bf[26];
    const float o3 = bf[3] + bf[11] + bf[19] + bf[27];
    const float o4 = bf[4] + bf[12] + bf[20] + bf[28];
    float* op = out + 1 + (size_t)b * NCLASS;
    op[0] = o0; op[1] = o1; op[2] = o2; op[3] = o3; op[4] = o4;
    const float m = fmaxf(fmaxf(fmaxf(o0, o1), fmaxf(o2, o3)), o4);
    const float sum = expf(o0 - m) + expf(o1 - m) + expf(o2 - m) +
                      expf(o3 - m) + expf(o4 - m);
    const int yb = y[b];
    const float oy = (yb == 0) ? o0 : (yb == 1) ? o1 : (yb == 2) ? o2
                   : (yb == 3) ? o3 : o4;
    const float nll = (m + logf(sum)) - oy;
    atomicAdd(out, nll * (1.0f / BATCH));
  }
}

extern "C" void kernel_launch(void* const* d_in, const int* in_sizes, int n_in,
                              void* d_out, int out_size, void* d_ws, size_t ws_size,
                              hipStream_t stream) {
  const float* zr = (const float*)d_in[0];
  const float* zi = (const float*)d_in[1];
  const float* th = (const float*)d_in[2];
  const int*   y  = (const int*)d_in[3];
  float* out = (float*)d_out;
  hipMemsetAsync(out, 0, sizeof(float), stream);  // zero loss accumulator
  qnn_sim<<<BATCH, 256, 0, stream>>>(zr, zi, th, y, out);
}